// Round 1
// baseline (476.444 us; speedup 1.0000x reference)
//
#include <hip/hip_runtime.h>
#include <math.h>

#define NN 100000
#define NE 1600000
#define D 64
#define INDIM 18

__device__ __forceinline__ float gelu_exact(float x) {
    return 0.5f * x * (1.0f + erff(x * 0.70710678118654752f));
}

// ---------------- project: h[n,:] = mlp(concat(x,grid)) ----------------
__global__ __launch_bounds__(256) void project_kernel(
    const float* __restrict__ x, const float* __restrict__ grid,
    const float* __restrict__ w1, const float* __restrict__ b1,
    const float* __restrict__ w2, const float* __restrict__ b2,
    float* __restrict__ h)
{
    __shared__ float s_w1[INDIM * D];
    __shared__ float s_w2[D * D];
    __shared__ float s_b1[D];
    __shared__ float s_b2[D];
    for (int i = threadIdx.x; i < INDIM * D; i += 256) s_w1[i] = w1[i];
    for (int i = threadIdx.x; i < D * D; i += 256) s_w2[i] = w2[i];
    for (int i = threadIdx.x; i < D; i += 256) { s_b1[i] = b1[i]; s_b2[i] = b2[i]; }
    __syncthreads();

    int n = blockIdx.x * 256 + threadIdx.x;
    if (n >= NN) return;

    float in[INDIM];
    {
        const float4* xr = (const float4*)(x + (size_t)n * 16);
        float4 a = xr[0], b = xr[1], c = xr[2], d = xr[3];
        in[0]=a.x; in[1]=a.y; in[2]=a.z; in[3]=a.w;
        in[4]=b.x; in[5]=b.y; in[6]=b.z; in[7]=b.w;
        in[8]=c.x; in[9]=c.y; in[10]=c.z; in[11]=c.w;
        in[12]=d.x; in[13]=d.y; in[14]=d.z; in[15]=d.w;
        float2 g = *(const float2*)(grid + (size_t)n * 2);
        in[16]=g.x; in[17]=g.y;
    }

    float mid[D];
    #pragma unroll 4
    for (int j = 0; j < D; ++j) {
        float acc = s_b1[j];
        #pragma unroll
        for (int k = 0; k < INDIM; ++k) acc += in[k] * s_w1[k * D + j];
        mid[j] = gelu_exact(acc);
    }

    float* hrow = h + (size_t)n * D;
    #pragma unroll 4
    for (int j = 0; j < D; ++j) {
        float acc = s_b2[j];
        #pragma unroll
        for (int k = 0; k < D; ++k) acc += mid[k] * s_w2[k * D + j];
        hrow[j] = acc;
    }
}

// ---------------- aggregate: aggr[dst,:] += h[src,:] (wave per edge) ----
__global__ __launch_bounds__(256) void aggregate_kernel(
    const int* __restrict__ ei, const float* __restrict__ h,
    float* __restrict__ aggr)
{
    int t = blockIdx.x * 256 + threadIdx.x;
    int e = t >> 6;
    int lane = t & 63;
    if (e >= NE) return;
    int src = ei[e];
    int dst = ei[NE + e];
    float v = h[(size_t)src * D + lane];
    atomicAdd(&aggr[(size_t)dst * D + lane], v);
}

// ---------------- update (W-mlp + aggr, gelu) + decode -----------------
__global__ __launch_bounds__(256) void update_decode_kernel(
    const float* __restrict__ h, const float* __restrict__ aggr,
    const float* __restrict__ ww1, const float* __restrict__ wb1,
    const float* __restrict__ ww2, const float* __restrict__ wb2,
    const float* __restrict__ dw1, const float* __restrict__ db1,
    const float* __restrict__ dw2, const float* __restrict__ db2,
    float* __restrict__ out)
{
    __shared__ float s_ww1[D * D];
    __shared__ float s_ww2[D * D];
    __shared__ float s_dw1[D * D];
    __shared__ float s_wb1[D], s_wb2[D], s_db1[D], s_dw2[D];
    __shared__ float s_db2;
    for (int i = threadIdx.x; i < D * D; i += 256) {
        s_ww1[i] = ww1[i];
        s_ww2[i] = ww2[i];
        s_dw1[i] = dw1[i];
    }
    for (int i = threadIdx.x; i < D; i += 256) {
        s_wb1[i] = wb1[i]; s_wb2[i] = wb2[i]; s_db1[i] = db1[i]; s_dw2[i] = dw2[i];
    }
    if (threadIdx.x == 0) s_db2 = db2[0];
    __syncthreads();

    int n = blockIdx.x * 256 + threadIdx.x;
    if (n >= NN) return;

    float hrow[D];
    #pragma unroll
    for (int j = 0; j < D; j += 4) {
        float4 v = *(const float4*)(h + (size_t)n * D + j);
        hrow[j] = v.x; hrow[j+1] = v.y; hrow[j+2] = v.z; hrow[j+3] = v.w;
    }

    // t = gelu(h @ ww1 + wb1)
    float t[D];
    #pragma unroll 4
    for (int j = 0; j < D; ++j) {
        float acc = s_wb1[j];
        #pragma unroll
        for (int k = 0; k < D; ++k) acc += hrow[k] * s_ww1[k * D + j];
        t[j] = gelu_exact(acc);
    }

    // u = gelu(t @ ww2 + wb2 + aggr)   (overwrite hrow)
    #pragma unroll 4
    for (int j = 0; j < D; ++j) {
        float acc = s_wb2[j] + aggr[(size_t)n * D + j];
        #pragma unroll
        for (int k = 0; k < D; ++k) acc += t[k] * s_ww2[k * D + j];
        hrow[j] = gelu_exact(acc);
    }

    // v = gelu(u @ dw1 + db1)          (overwrite t)
    #pragma unroll 4
    for (int j = 0; j < D; ++j) {
        float acc = s_db1[j];
        #pragma unroll
        for (int k = 0; k < D; ++k) acc += hrow[k] * s_dw1[k * D + j];
        t[j] = gelu_exact(acc);
    }

    // out = v @ dw2 + db2
    float acc = s_db2;
    #pragma unroll
    for (int k = 0; k < D; ++k) acc += t[k] * s_dw2[k];
    out[n] = acc;
}

extern "C" void kernel_launch(void* const* d_in, const int* in_sizes, int n_in,
                              void* d_out, int out_size, void* d_ws, size_t ws_size,
                              hipStream_t stream) {
    const float* x    = (const float*)d_in[0];
    const float* grid = (const float*)d_in[1];
    const int*   ei   = (const int*)d_in[2];
    // d_in[3] = edge_features (unused by the reference)
    const float* p_w1 = (const float*)d_in[4];
    const float* p_b1 = (const float*)d_in[5];
    const float* p_w2 = (const float*)d_in[6];
    const float* p_b2 = (const float*)d_in[7];
    const float* w_w1 = (const float*)d_in[8];
    const float* w_b1 = (const float*)d_in[9];
    const float* w_w2 = (const float*)d_in[10];
    const float* w_b2 = (const float*)d_in[11];
    const float* d_w1 = (const float*)d_in[12];
    const float* d_b1 = (const float*)d_in[13];
    const float* d_w2 = (const float*)d_in[14];
    const float* d_b2 = (const float*)d_in[15];
    float* out = (float*)d_out;

    float* h    = (float*)d_ws;                  // [NN, D]
    float* aggr = h + (size_t)NN * D;            // [NN, D]

    hipMemsetAsync(aggr, 0, (size_t)NN * D * sizeof(float), stream);

    project_kernel<<<(NN + 255) / 256, 256, 0, stream>>>(
        x, grid, p_w1, p_b1, p_w2, p_b2, h);

    // one wave (64 lanes) per edge, lane = feature dim
    aggregate_kernel<<<(size_t)NE * 64 / 256, 256, 0, stream>>>(ei, h, aggr);

    update_decode_kernel<<<(NN + 255) / 256, 256, 0, stream>>>(
        h, aggr, w_w1, w_b1, w_w2, w_b2, d_w1, d_b1, d_w2, d_b2, out);
}

// Round 2
// 378.194 us; speedup vs baseline: 1.2598x; 1.2598x over previous
//
#include <hip/hip_runtime.h>
#include <math.h>

#define NN 100000
#define NE 1600000
#define D 64
#define INDIM 18
#define NB ((NN + 1023) / 1024)   // blocks in block-scan (98)

__device__ __forceinline__ float gelu_exact(float x) {
    return 0.5f * x * (1.0f + erff(x * 0.70710678118654752f));
}

// ---------------- project: h[n,:] = mlp(concat(x,grid)) ----------------
__global__ __launch_bounds__(256) void project_kernel(
    const float* __restrict__ x, const float* __restrict__ grid,
    const float* __restrict__ w1, const float* __restrict__ b1,
    const float* __restrict__ w2, const float* __restrict__ b2,
    float* __restrict__ h)
{
    __shared__ float s_w1[INDIM * D];
    __shared__ float s_w2[D * D];
    __shared__ float s_b1[D];
    __shared__ float s_b2[D];
    for (int i = threadIdx.x; i < INDIM * D; i += 256) s_w1[i] = w1[i];
    for (int i = threadIdx.x; i < D * D; i += 256) s_w2[i] = w2[i];
    for (int i = threadIdx.x; i < D; i += 256) { s_b1[i] = b1[i]; s_b2[i] = b2[i]; }
    __syncthreads();

    int n = blockIdx.x * 256 + threadIdx.x;
    if (n >= NN) return;

    float in[INDIM];
    {
        const float4* xr = (const float4*)(x + (size_t)n * 16);
        float4 a = xr[0], b = xr[1], c = xr[2], d = xr[3];
        in[0]=a.x; in[1]=a.y; in[2]=a.z; in[3]=a.w;
        in[4]=b.x; in[5]=b.y; in[6]=b.z; in[7]=b.w;
        in[8]=c.x; in[9]=c.y; in[10]=c.z; in[11]=c.w;
        in[12]=d.x; in[13]=d.y; in[14]=d.z; in[15]=d.w;
        float2 g = *(const float2*)(grid + (size_t)n * 2);
        in[16]=g.x; in[17]=g.y;
    }

    float mid[D];
    #pragma unroll 4
    for (int j = 0; j < D; ++j) {
        float acc = s_b1[j];
        #pragma unroll
        for (int k = 0; k < INDIM; ++k) acc += in[k] * s_w1[k * D + j];
        mid[j] = gelu_exact(acc);
    }

    float* hrow = h + (size_t)n * D;
    #pragma unroll 4
    for (int j = 0; j < D; ++j) {
        float acc = s_b2[j];
        #pragma unroll
        for (int k = 0; k < D; ++k) acc += mid[k] * s_w2[k * D + j];
        hrow[j] = acc;
    }
}

// ---------------- CSR build: histogram ----------------
__global__ __launch_bounds__(256) void count_kernel(
    const int* __restrict__ ei, int* __restrict__ deg)
{
    int e = blockIdx.x * 256 + threadIdx.x;
    if (e >= NE) return;
    atomicAdd(&deg[ei[NE + e]], 1);
}

// ---------------- CSR build: per-1024-block exclusive scan ----------------
__global__ __launch_bounds__(256) void scan_blocks_kernel(
    const int* __restrict__ deg, int* __restrict__ offs, int* __restrict__ bsum)
{
    __shared__ int s[256];
    int b = blockIdx.x;
    int base = b * 1024;
    int t = threadIdx.x;
    int v[4]; int sum = 0;
    #pragma unroll
    for (int i = 0; i < 4; ++i) {
        int idx = base + t * 4 + i;
        int d = (idx < NN) ? deg[idx] : 0;
        v[i] = sum; sum += d;
    }
    s[t] = sum; __syncthreads();
    for (int off = 1; off < 256; off <<= 1) {
        int val = s[t];
        int add = (t >= off) ? s[t - off] : 0;
        __syncthreads();
        s[t] = val + add;
        __syncthreads();
    }
    int texcl = s[t] - sum;
    #pragma unroll
    for (int i = 0; i < 4; ++i) {
        int idx = base + t * 4 + i;
        if (idx < NN) offs[idx] = texcl + v[i];
    }
    if (t == 255) bsum[b] = s[255];
}

// ---------------- CSR build: scan the 98 block sums (1 block) ----------------
__global__ __launch_bounds__(128) void scan_bsum_kernel(int* __restrict__ bsum)
{
    __shared__ int s[128];
    int t = threadIdx.x;
    int v = (t < NB) ? bsum[t] : 0;
    s[t] = v; __syncthreads();
    for (int off = 1; off < 128; off <<= 1) {
        int val = s[t];
        int add = (t >= off) ? s[t - off] : 0;
        __syncthreads();
        s[t] = val + add;
        __syncthreads();
    }
    if (t < NB) bsum[t] = s[t] - v;   // exclusive
}

// ---------------- CSR build: finalize offsets + init cursors ----------------
__global__ __launch_bounds__(256) void add_offsets_kernel(
    int* __restrict__ offs, const int* __restrict__ bsum, int* __restrict__ cursor)
{
    int i = blockIdx.x * 256 + threadIdx.x;
    if (i < NN) {
        int o = offs[i] + bsum[i >> 10];
        offs[i] = o;
        cursor[i] = o;
    }
    if (i == 0) offs[NN] = NE;
}

// ---------------- CSR build: scatter src indices into buckets ----------------
__global__ __launch_bounds__(256) void scatter_kernel(
    const int* __restrict__ ei, int* __restrict__ cursor, int* __restrict__ esrc)
{
    int e = blockIdx.x * 256 + threadIdx.x;
    if (e >= NE) return;
    int dst = ei[NE + e];
    int src = ei[e];
    int pos = atomicAdd(&cursor[dst], 1);
    esrc[pos] = src;
}

// ---------------- aggregate via CSR: one wave per node, lane = dim -----
__global__ __launch_bounds__(256) void aggregate_csr_kernel(
    const int* __restrict__ offs, const int* __restrict__ esrc,
    const float* __restrict__ h, float* __restrict__ aggr)
{
    int t = blockIdx.x * 256 + threadIdx.x;
    int n = t >> 6;
    int lane = t & 63;
    if (n >= NN) return;
    int start = offs[n], end = offs[n + 1];
    float a0 = 0.f, a1 = 0.f, a2 = 0.f, a3 = 0.f;
    int e = start;
    for (; e + 4 <= end; e += 4) {
        int s0 = esrc[e], s1 = esrc[e + 1], s2 = esrc[e + 2], s3 = esrc[e + 3];
        a0 += h[(size_t)s0 * D + lane];
        a1 += h[(size_t)s1 * D + lane];
        a2 += h[(size_t)s2 * D + lane];
        a3 += h[(size_t)s3 * D + lane];
    }
    for (; e < end; ++e) a0 += h[(size_t)esrc[e] * D + lane];
    aggr[(size_t)n * D + lane] = (a0 + a1) + (a2 + a3);
}

// ---------------- legacy atomic aggregate (ws fallback) ----------------
__global__ __launch_bounds__(256) void aggregate_kernel(
    const int* __restrict__ ei, const float* __restrict__ h,
    float* __restrict__ aggr)
{
    int t = blockIdx.x * 256 + threadIdx.x;
    int e = t >> 6;
    int lane = t & 63;
    if (e >= NE) return;
    int src = ei[e];
    int dst = ei[NE + e];
    float v = h[(size_t)src * D + lane];
    atomicAdd(&aggr[(size_t)dst * D + lane], v);
}

// ---------------- update (W-mlp + aggr, gelu) + decode -----------------
__global__ __launch_bounds__(256) void update_decode_kernel(
    const float* __restrict__ h, const float* __restrict__ aggr,
    const float* __restrict__ ww1, const float* __restrict__ wb1,
    const float* __restrict__ ww2, const float* __restrict__ wb2,
    const float* __restrict__ dw1, const float* __restrict__ db1,
    const float* __restrict__ dw2, const float* __restrict__ db2,
    float* __restrict__ out)
{
    __shared__ float s_ww1[D * D];
    __shared__ float s_ww2[D * D];
    __shared__ float s_dw1[D * D];
    __shared__ float s_wb1[D], s_wb2[D], s_db1[D], s_dw2[D];
    __shared__ float s_db2;
    for (int i = threadIdx.x; i < D * D; i += 256) {
        s_ww1[i] = ww1[i];
        s_ww2[i] = ww2[i];
        s_dw1[i] = dw1[i];
    }
    for (int i = threadIdx.x; i < D; i += 256) {
        s_wb1[i] = wb1[i]; s_wb2[i] = wb2[i]; s_db1[i] = db1[i]; s_dw2[i] = dw2[i];
    }
    if (threadIdx.x == 0) s_db2 = db2[0];
    __syncthreads();

    int n = blockIdx.x * 256 + threadIdx.x;
    if (n >= NN) return;

    float hrow[D];
    #pragma unroll
    for (int j = 0; j < D; j += 4) {
        float4 v = *(const float4*)(h + (size_t)n * D + j);
        hrow[j] = v.x; hrow[j+1] = v.y; hrow[j+2] = v.z; hrow[j+3] = v.w;
    }

    float t[D];
    #pragma unroll 4
    for (int j = 0; j < D; ++j) {
        float acc = s_wb1[j];
        #pragma unroll
        for (int k = 0; k < D; ++k) acc += hrow[k] * s_ww1[k * D + j];
        t[j] = gelu_exact(acc);
    }

    #pragma unroll 4
    for (int j = 0; j < D; ++j) {
        float acc = s_wb2[j] + aggr[(size_t)n * D + j];
        #pragma unroll
        for (int k = 0; k < D; ++k) acc += t[k] * s_ww2[k * D + j];
        hrow[j] = gelu_exact(acc);
    }

    #pragma unroll 4
    for (int j = 0; j < D; ++j) {
        float acc = s_db1[j];
        #pragma unroll
        for (int k = 0; k < D; ++k) acc += hrow[k] * s_dw1[k * D + j];
        t[j] = gelu_exact(acc);
    }

    float acc = s_db2;
    #pragma unroll
    for (int k = 0; k < D; ++k) acc += t[k] * s_dw2[k];
    out[n] = acc;
}

extern "C" void kernel_launch(void* const* d_in, const int* in_sizes, int n_in,
                              void* d_out, int out_size, void* d_ws, size_t ws_size,
                              hipStream_t stream) {
    const float* x    = (const float*)d_in[0];
    const float* grid = (const float*)d_in[1];
    const int*   ei   = (const int*)d_in[2];
    const float* p_w1 = (const float*)d_in[4];
    const float* p_b1 = (const float*)d_in[5];
    const float* p_w2 = (const float*)d_in[6];
    const float* p_b2 = (const float*)d_in[7];
    const float* w_w1 = (const float*)d_in[8];
    const float* w_b1 = (const float*)d_in[9];
    const float* w_w2 = (const float*)d_in[10];
    const float* w_b2 = (const float*)d_in[11];
    const float* d_w1 = (const float*)d_in[12];
    const float* d_b1 = (const float*)d_in[13];
    const float* d_w2 = (const float*)d_in[14];
    const float* d_b2 = (const float*)d_in[15];
    float* out = (float*)d_out;

    float* h    = (float*)d_ws;                  // [NN, D]
    float* aggr = h + (size_t)NN * D;            // [NN, D]
    int*   deg  = (int*)(aggr + (size_t)NN * D); // [NN]  (reused as cursor)
    int*   offs = deg + NN;                      // [NN+1]
    int*   bsum = offs + NN + 1;                 // [128]
    int*   esrc = bsum + 128;                    // [NE]

    size_t need = ((size_t)NN * D * 2) * 4 + ((size_t)NN * 2 + 1 + 128 + NE) * 4;

    project_kernel<<<(NN + 255) / 256, 256, 0, stream>>>(
        x, grid, p_w1, p_b1, p_w2, p_b2, h);

    if (ws_size >= need) {
        // ---- CSR build + atomic-free aggregation ----
        hipMemsetAsync(deg, 0, (size_t)NN * sizeof(int), stream);
        count_kernel<<<(NE + 255) / 256, 256, 0, stream>>>(ei, deg);
        scan_blocks_kernel<<<NB, 256, 0, stream>>>(deg, offs, bsum);
        scan_bsum_kernel<<<1, 128, 0, stream>>>(bsum);
        add_offsets_kernel<<<(NN + 255) / 256, 256, 0, stream>>>(offs, bsum, deg /*cursor*/);
        scatter_kernel<<<(NE + 255) / 256, 256, 0, stream>>>(ei, deg /*cursor*/, esrc);
        aggregate_csr_kernel<<<(NN * 64 + 255) / 256, 256, 0, stream>>>(offs, esrc, h, aggr);
    } else {
        // ---- fallback: atomic aggregation ----
        hipMemsetAsync(aggr, 0, (size_t)NN * D * sizeof(float), stream);
        aggregate_kernel<<<(size_t)NE * 64 / 256, 256, 0, stream>>>(ei, h, aggr);
    }

    update_decode_kernel<<<(NN + 255) / 256, 256, 0, stream>>>(
        h, aggr, w_w1, w_b1, w_w2, w_b2, d_w1, d_b1, d_w2, d_b2, out);
}